// Round 3
// baseline (1552.828 us; speedup 1.0000x reference)
//
#include <hip/hip_runtime.h>
#include <stdint.h>

typedef unsigned short u16;
typedef unsigned int u32;
typedef __attribute__((ext_vector_type(8))) short bf16x8;
typedef __attribute__((ext_vector_type(4))) float f32x4;

#define T_SEQ 8192
#define DM 1024
#define HD 256

__device__ __forceinline__ u16 f2bf(float f) {
  u32 u = __float_as_uint(f);
  u32 r = (u + 0x7fffu + ((u >> 16) & 1u)) >> 16;
  return (u16)r;
}
__device__ __forceinline__ float bf2f(u16 u) {
  return __uint_as_float(((u32)u) << 16);
}
__device__ __forceinline__ f32x4 mfma16(bf16x8 a, bf16x8 b, f32x4 c) {
  return __builtin_amdgcn_mfma_f32_16x16x32_bf16(a, b, c, 0, 0, 0);
}
// async global->LDS, 16B per lane. LDS dest must be wave-uniform base + lane*16.
__device__ __forceinline__ void gl2lds16(const u16* g, u16* l) {
  __builtin_amdgcn_global_load_lds(
      (const __attribute__((address_space(1))) u32*)(uintptr_t)g,
      (__attribute__((address_space(3))) u32*)(u32)(uintptr_t)l, 16, 0, 0);
}

// ---------------- fp32 -> bf16 bulk convert ----------------
__global__ __launch_bounds__(256) void kconv(const float* __restrict__ src, u16* __restrict__ dst, int n4) {
  int i = blockIdx.x * 256 + threadIdx.x;
  if (i < n4) {
    float4 v = reinterpret_cast<const float4*>(src)[i];
    ushort4 s;
    s.x = f2bf(v.x); s.y = f2bf(v.y); s.z = f2bf(v.z); s.w = f2bf(v.w);
    reinterpret_cast<ushort4*>(dst)[i] = s;
  }
}

// ---------------- K1: xb16 + per-head-normalized rk (both (B,T,D) bf16) ----------------
__global__ __launch_bounds__(256) void k_rk(const float* __restrict__ x, u16* __restrict__ xb, u16* __restrict__ rk) {
  const int row = blockIdx.x;
  const int t = threadIdx.x;
  const size_t base = (size_t)row * DM + t * 4;
  float4 v = *reinterpret_cast<const float4*>(&x[base]);
  ushort4 s;
  s.x = f2bf(v.x); s.y = f2bf(v.y); s.z = f2bf(v.z); s.w = f2bf(v.w);
  *reinterpret_cast<ushort4*>(&xb[base]) = s;
  float ss = v.x * v.x + v.y * v.y + v.z * v.z + v.w * v.w;
#pragma unroll
  for (int m = 1; m < 64; m <<= 1) ss += __shfl_xor(ss, m, 64);
  float inv = 1.0f / fmaxf(sqrtf(ss), 1e-12f);
  ushort4 r;
  r.x = f2bf(v.x * inv); r.y = f2bf(v.y * inv); r.z = f2bf(v.z * inv); r.w = f2bf(v.w * inv);
  *reinterpret_cast<ushort4*>(&rk[base]) = r;
}

// ---------------- GEMM: C[M,N] = A[M,K] @ Bt[N,K]^T (bf16 in, fp32 acc) ----------------
template <bool STORE_BF16>
__global__ __launch_bounds__(256) void gemm_bt(const u16* __restrict__ A, const u16* __restrict__ Bt,
                                               u16* __restrict__ Cb, float* __restrict__ Cf,
                                               const float* __restrict__ addin, int M, int N, int K) {
  __shared__ __align__(16) u16 As[128 * 64];
  __shared__ __align__(16) u16 Bs[128 * 64];
  const int tiles_n = N >> 7;
  const int tm = (blockIdx.x / tiles_n) << 7;
  const int tn = (blockIdx.x % tiles_n) << 7;
  const int t = threadIdx.x;
  const int w = t >> 6, l = t & 63;
  const int lane15 = l & 15, quad = l >> 4;
  const int wm = w & 1, wn = w >> 1;
  const int r0 = t >> 3;          // 0..31
  const int kc = (t & 7) << 3;    // 0..56 (u16 units, 16B chunks)

  f32x4 acc[4][4];
#pragma unroll
  for (int mi = 0; mi < 4; ++mi)
#pragma unroll
    for (int ni = 0; ni < 4; ++ni) acc[mi][ni] = (f32x4){0.f, 0.f, 0.f, 0.f};

  const int NK = K >> 6;
#pragma unroll 1
  for (int kt = 0; kt < NK; ++kt) {
    __syncthreads();
    const int k0 = kt << 6;
#pragma unroll
    for (int j = 0; j < 4; ++j) {
      gl2lds16(&A[(size_t)(tm + r0 + j * 32) * K + k0 + kc], &As[(r0 + j * 32) * 64 + kc]);
      gl2lds16(&Bt[(size_t)(tn + r0 + j * 32) * K + k0 + kc], &Bs[(r0 + j * 32) * 64 + kc]);
    }
    __syncthreads();
#pragma unroll
    for (int kk = 0; kk < 2; ++kk) {
      bf16x8 af[4], bfr[4];
#pragma unroll
      for (int mi = 0; mi < 4; ++mi)
        af[mi] = *reinterpret_cast<const bf16x8*>(&As[(wm * 64 + mi * 16 + lane15) * 64 + kk * 32 + quad * 8]);
#pragma unroll
      for (int ni = 0; ni < 4; ++ni)
        bfr[ni] = *reinterpret_cast<const bf16x8*>(&Bs[(wn * 64 + ni * 16 + lane15) * 64 + kk * 32 + quad * 8]);
#pragma unroll
      for (int mi = 0; mi < 4; ++mi)
#pragma unroll
        for (int ni = 0; ni < 4; ++ni) acc[mi][ni] = mfma16(af[mi], bfr[ni], acc[mi][ni]);
    }
  }
#pragma unroll
  for (int mi = 0; mi < 4; ++mi)
#pragma unroll
    for (int ni = 0; ni < 4; ++ni)
#pragma unroll
      for (int r = 0; r < 4; ++r) {
        int row = tm + wm * 64 + mi * 16 + quad * 4 + r;
        int col = tn + wn * 64 + ni * 16 + lane15;
        size_t idx = (size_t)row * N + col;
        float vv = acc[mi][ni][r];
        if (STORE_BF16) Cb[idx] = f2bf(vv);
        else Cf[idx] = vv + addin[idx];
      }
}

// ---------------- K2 (MFMA rewrite): per-chunk A0, blocked inv, intra, vA, wkA, wkgT ----------------
// One block per (bh, n) chunk. 256 threads = 4 waves. ~111 KB LDS -> 1 block/CU.
__global__ __launch_bounds__(256, 1) void k2(const u16* __restrict__ rk, const u16* __restrict__ v,
                                             u16* __restrict__ vA, u16* __restrict__ wkA,
                                             u16* __restrict__ wkgT, u16* __restrict__ intra,
                                             const float* __restrict__ decay) {
  __shared__ __align__(16) u16 sk[65][264];     // wk_ext rows (row r = token n*64-1+r), bf16
  __shared__ __align__(16) u16 tT[256][72];     // transposed operand (wkT, then vT)
  __shared__ __align__(16) float Am[64][68];    // A0 (strict lower valid), f32
  __shared__ __align__(16) float Xm[64][68];    // X = inv(I - A0), full explicit
  __shared__ __align__(16) float tmpT[4][16][20];
  __shared__ float gp[65];
  const int bx = blockIdx.x;
  const int bh = bx >> 7, n = bx & 127;
  const int b = bh >> 2, h = bh & 3;
  const int t = threadIdx.x;
  const int w = t >> 6, l = t & 63;
  const int lane15 = l & 15, quad = l >> 4;
  const int li = l & 15, jq = l >> 4;

  if (t <= 64) {
    float gamma = 1.0f / (1.0f + __expf(-decay[h]));
    gp[t] = __powf(gamma, (float)t);
  }
  // zero Am, Xm (incl pad)
  for (int i = t; i < 64 * 68; i += 256) {
    (&Am[0][0])[i] = 0.0f;
    (&Xm[0][0])[i] = 0.0f;
  }
  // stage sk (row-major) + wkT (transposed) from global rk
  for (int i = t; i < 65 * 32; i += 256) {
    const int r = i >> 5, c16 = i & 31;
    const int g = n * 64 - 1 + r;
    uint4 val = make_uint4(0, 0, 0, 0);
    if (g >= 0) val = *reinterpret_cast<const uint4*>(&rk[((size_t)(b * T_SEQ + g)) * DM + h * HD + c16 * 8]);
    *reinterpret_cast<uint4*>(&sk[r][c16 * 8]) = val;
    if (r < 64) {
      u16 e[8];
      e[0] = val.x & 0xffff; e[1] = val.x >> 16;
      e[2] = val.y & 0xffff; e[3] = val.y >> 16;
      e[4] = val.z & 0xffff; e[5] = val.z >> 16;
      e[6] = val.w & 0xffff; e[7] = val.w >> 16;
#pragma unroll
      for (int ee = 0; ee < 8; ++ee) tT[c16 * 8 + ee][r] = e[ee];
    }
  }
  __syncthreads();

  // ---- step 1: M_ww = wk@wk^T (waves 0,1), M_rw = rk@wk^T (waves 2,3) via MFMA ----
  {
    const int prod = w >> 1;          // 0: ww, 1: rw
    const int tib = (w & 1) * 2;      // ti in {tib, tib+1}
    f32x4 s1[2][4];
#pragma unroll
    for (int a = 0; a < 2; ++a)
#pragma unroll
      for (int tj = 0; tj < 4; ++tj) s1[a][tj] = (f32x4){0.f, 0.f, 0.f, 0.f};
#pragma unroll
    for (int ks = 0; ks < 8; ++ks) {
      bf16x8 afr[2], bfr[4];
#pragma unroll
      for (int a = 0; a < 2; ++a)
        afr[a] = *reinterpret_cast<const bf16x8*>(&sk[(tib + a) * 16 + lane15 + prod][ks * 32 + quad * 8]);
#pragma unroll
      for (int tj = 0; tj < 4; ++tj)
        bfr[tj] = *reinterpret_cast<const bf16x8*>(&sk[tj * 16 + lane15][ks * 32 + quad * 8]);
#pragma unroll
      for (int a = 0; a < 2; ++a)
#pragma unroll
        for (int tj = 0; tj < 4; ++tj) s1[a][tj] = mfma16(afr[a], bfr[tj], s1[a][tj]);
    }
    if (prod == 0) {
#pragma unroll
      for (int a = 0; a < 2; ++a)
#pragma unroll
        for (int tj = 0; tj < 4; ++tj)
#pragma unroll
          for (int r = 0; r < 4; ++r) {
            const int i = (tib + a) * 16 + quad * 4 + r, j = tj * 16 + lane15;
            if (j < i) Am[i][j] = -s1[a][tj][r] * gp[i - j];
          }
    } else {
      u16* intra_n = intra + (size_t)bx * 4096;
#pragma unroll
      for (int a = 0; a < 2; ++a)
#pragma unroll
        for (int tj = 0; tj < 4; ++tj)
#pragma unroll
          for (int r = 0; r < 4; ++r) {
            const int i = (tib + a) * 16 + quad * 4 + r, j = tj * 16 + lane15;
            intra_n[i * 64 + j] = (j < i) ? f2bf(s1[a][tj][r] * gp[i - j]) : (u16)0;
          }
    }
  }
  __syncthreads();

  // ---- step 2a: invert diagonal 16x16 blocks (wave w -> block w), column-parallel ----
  if (l < 16) {
    const int bi = w * 16;
    const int j = l;
    Xm[bi + j][bi + j] = 1.0f;
    for (int i = 1; i < 16; ++i) {
      if (j < i) {
        float acc = Am[bi + i][bi + j];
        for (int k = j + 1; k < i; ++k) acc += Am[bi + i][bi + k] * Xm[bi + k][bi + j];
        Xm[bi + i][bi + j] = acc;
      }
    }
  }
  __syncthreads();

  // ---- step 2b: off-diagonal blocks, levels 1..3: X(I,J) = X(I,I) * sum_K A0(I,K) X(K,J) ----
  for (int lvl = 1; lvl < 4; ++lvl) {
    if (w + lvl < 4) {
      const int I = w + lvl, J = w;
      float a4[4] = {0.f, 0.f, 0.f, 0.f};
      for (int K = J; K < I; ++K) {
#pragma unroll
        for (int k = 0; k < 16; ++k) {
          const float a = Am[I * 16 + li][K * 16 + k];
          const float* xr = &Xm[K * 16 + k][J * 16 + jq * 4];
          a4[0] += a * xr[0]; a4[1] += a * xr[1]; a4[2] += a * xr[2]; a4[3] += a * xr[3];
        }
      }
#pragma unroll
      for (int r = 0; r < 4; ++r) tmpT[w][li][jq * 4 + r] = a4[r];
      asm volatile("" ::: "memory");
      float b4[4] = {0.f, 0.f, 0.f, 0.f};
#pragma unroll
      for (int k = 0; k < 16; ++k) {
        const float a = Xm[I * 16 + li][I * 16 + k];
        const float* tr = &tmpT[w][k][jq * 4];
        b4[0] += a * tr[0]; b4[1] += a * tr[1]; b4[2] += a * tr[2]; b4[3] += a * tr[3];
      }
#pragma unroll
      for (int r = 0; r < 4; ++r) Xm[I * 16 + li][J * 16 + jq * 4 + r] = b4[r];
    }
    __syncthreads();
  }

  // ---- step 3: products X @ wk (then X @ v) via MFMA; output (C x d) row-major bf16 ----
  auto product = [&](u16* dst) {
    bf16x8 afr[2];
#pragma unroll
    for (int ks = 0; ks < 2; ++ks) {
      const float* xr = &Xm[w * 16 + lane15][ks * 32 + quad * 8];
      bf16x8 f;
#pragma unroll
      for (int e = 0; e < 8; ++e) ((u16*)&f)[e] = f2bf(xr[e]);
      afr[ks] = f;
    }
#pragma unroll
    for (int nj = 0; nj < 16; ++nj) {
      f32x4 acc = (f32x4){0.f, 0.f, 0.f, 0.f};
#pragma unroll
      for (int ks = 0; ks < 2; ++ks) {
        bf16x8 bfr = *reinterpret_cast<const bf16x8*>(&tT[nj * 16 + lane15][ks * 32 + quad * 8]);
        acc = mfma16(afr[ks], bfr, acc);
      }
#pragma unroll
      for (int r = 0; r < 4; ++r)
        dst[(size_t)(w * 16 + quad * 4 + r) * 256 + nj * 16 + lane15] = f2bf(acc[r]);
    }
  };
  product(wkA + (size_t)bx * (64 * 256));
  // wkgT[i][c] = wk[c][i] * gamma^(63-c) = wkT[i][c] * gp[63-c], layout (d, C)
  {
    u16* wkg_n = wkgT + (size_t)bx * (256 * 64);
    const int i = t;
#pragma unroll
    for (int c16 = 0; c16 < 8; ++c16) {
      bf16x8 rv = *reinterpret_cast<const bf16x8*>(&tT[i][c16 * 8]);
      bf16x8 ov;
#pragma unroll
      for (int e = 0; e < 8; ++e)
        ((u16*)&ov)[e] = f2bf(bf2f(((u16*)&rv)[e]) * gp[63 - (c16 * 8 + e)]);
      *reinterpret_cast<bf16x8*>(&wkg_n[i * 64 + c16 * 8]) = ov;
    }
  }
  __syncthreads();  // all tT (wkT) reads done
  // stage vT
  for (int i = t; i < 64 * 32; i += 256) {
    const int r = i >> 5, c16 = i & 31;
    uint4 val = *reinterpret_cast<const uint4*>(&v[((size_t)(b * T_SEQ + n * 64 + r)) * DM + h * HD + c16 * 8]);
    u16 e[8];
    e[0] = val.x & 0xffff; e[1] = val.x >> 16;
    e[2] = val.y & 0xffff; e[3] = val.y >> 16;
    e[4] = val.z & 0xffff; e[5] = val.z >> 16;
    e[6] = val.w & 0xffff; e[7] = val.w >> 16;
#pragma unroll
    for (int ee = 0; ee < 8; ++ee) tT[c16 * 8 + ee][r] = e[ee];
  }
  __syncthreads();
  product(vA + (size_t)bx * (64 * 256));
}

// ---------------- K3: sequential scan; XCD-swizzled; register double-buffer; ----------------
// TWO independent 4-wave scan teams per 512-thread block (same bh, adjacent j-slices) so each
// SIMD holds 2 waves from independent dependency graphs -> latency stalls overlap.
// __launch_bounds__(512, 1): NO VGPR cap (round 2's (512,2) forced 128 VGPR -> full spill of
// the register double-buffer -> 3x regression). One 8-wave block/CU = 2 waves/SIMD by placement.
__global__ __launch_bounds__(512, 1) void k3(const u16* __restrict__ rk, const u16* __restrict__ vA,
                                             const u16* __restrict__ wkA, const u16* __restrict__ wkgT,
                                             const u16* __restrict__ intra, const float* __restrict__ decay,
                                             const float* __restrict__ log_alpha, u16* __restrict__ o) {
  __shared__ __align__(16) u16 STb[2][16][264];   // per-team S^T bf16 copy: [jl][i], padded
  __shared__ __align__(16) u16 vnT[2][16][72];    // per-team v_new^T [jl][c]
  // XCD swizzle: all 8 blocks of one bh land on the same XCD (round-robin dispatch)
  const int bh = blockIdx.x & 7, jb = blockIdx.x >> 3;   // jb 0..7
  const int b = bh >> 2, h = bh & 3;
  const int t = threadIdx.x;                 // 0..511
  const int team = t >> 8;                   // 0,1: independent scan instance
  const int w = (t >> 6) & 3, l = t & 63;    // wave-in-team, lane
  const int j0 = jb * 32 + team * 16;
  const int lane15 = l & 15, quad = l >> 4;
  const float gamma = 1.0f / (1.0f + __expf(-decay[h]));
  const float alpha = __expf(log_alpha[h]);
  const float gC = __powf(gamma, 64.0f);
  const int c = w * 16 + lane15;             // chunk-row this lane owns in phases A/B
  const float gc = __powf(gamma, (float)c);
  for (int i = t; i < 4224; i += 512) reinterpret_cast<u32*>(&STb[0][0][0])[i] = 0u;
  f32x4 Sacc[4];
#pragma unroll
  for (int nt = 0; nt < 4; ++nt) Sacc[nt] = (f32x4){0.f, 0.f, 0.f, 0.f};

  const size_t chb = (size_t)bh * 128;
  const u16* wkA_b = wkA + chb * (64 * 256);
  const u16* vA_b = vA + chb * (64 * 256);
  const u16* wkg_b = wkgT + chb * (256 * 64);
  const u16* intr_b = intra + chb * 4096;
  const u16* rk_b = rk + ((size_t)(b * T_SEQ)) * DM + h * HD;

  // Double-buffered per-step register staging (token-pasted names; all indices compile-time).
  bf16x8 AwkA[8], Ark[8], Awkg[8], Ain[2]; ushort4 AvA;
  bf16x8 BwkA[8], Brk[8], Bwkg[8], Bin[2]; ushort4 BvA;

  // Loads ordered by first use: wkA (phase A) -> vA -> rk (A2) -> intra (B) -> wkg (C).
#define LOADB(P, n_) do {                                                                  \
    const u16* wkA_n = wkA_b + (size_t)(n_) * (64 * 256);                                  \
    const u16* vA_n = vA_b + (size_t)(n_) * (64 * 256);                                    \
    const u16* wkg_n = wkg_b + (size_t)(n_) * (256 * 64);                                  \
    const u16* intr_n = intr_b + (size_t)(n_) * 4096;                                      \
    const u16* rk_n = rk_b + (size_t)(n_) * 64 * DM;                                       \
    const u16* wrow = wkA_n + c * 256 + quad * 8;                                          \
    _Pragma("unroll")                                                                      \
    for (int kt = 0; kt < 8; ++kt) P##wkA[kt] = *reinterpret_cast<const bf16x8*>(&wrow[kt * 32]); \
    P##vA = *reinterpret_cast<const ushort4*>(&vA_n[c * 256 + j0 + quad * 4]);             \
    const u16* rrow = rk_n + (size_t)c * DM + quad * 8;                                    \
    _Pragma("unroll")                                                                      \
    for (int kt = 0; kt < 8; ++kt) P##rk[kt] = *reinterpret_cast<const bf16x8*>(&rrow[kt * 32]); \
    const u16* irow = intr_n + c * 64 + quad * 8;                                          \
    _Pragma("unroll")                                                                      \
    for (int kt = 0; kt < 2; ++kt) P##in[kt] = *reinterpret_cast<const bf16x8*>(&irow[kt * 32]); \
    _Pragma("unroll")                                                                      \
    for (int nt = 0; nt < 4; ++nt)                                                         \
      _Pragma("unroll")                                                                    \
      for (int kt = 0; kt < 2; ++kt)                                                       \
        P##wkg[nt * 2 + kt] =                                                              \
            *reinterpret_cast<const bf16x8*>(&wkg_n[(size_t)(w * 64 + nt * 16 + lane15) * 64 + kt * 32 + quad * 8]); \
  } while (0)

  // Raw barrier: make this wave's LDS ops visible (lgkmcnt(0)), sync, pin scheduler.
  // Crucially does NOT drain vmcnt -> prefetched global loads stay in flight.
#define KBAR() do {                                              \
    asm volatile("s_waitcnt lgkmcnt(0)" ::: "memory");           \
    __builtin_amdgcn_s_barrier();                                \
    __builtin_amdgcn_sched_barrier(0);                           \
  } while (0)

#define STEP(P, Q, n_, do_pf) do {                                                         \
    if (do_pf) LOADB(Q, (n_) + 1); /* issue next step's loads before waiting */            \
    KBAR(); /* (a) STb from prev phase C visible */                                        \
    bf16x8 aS[8];                                                                          \
    _Pragma("unroll")                                                                      \
    for (int kt = 0; kt < 8; ++kt)                                                         \
      aS[kt] = *reinterpret_cast<const bf16x8*>(&STb[team][lane15][kt * 32 + quad * 8]);   \
    /* phase A: P^T = S^T @ wkA^T (2 parallel 4-chains); v_new^T = vA^T - P^T */           \
    f32x4 a0 = (f32x4){0.f, 0.f, 0.f, 0.f}, a1 = (f32x4){0.f, 0.f, 0.f, 0.f};              \
    _Pragma("unroll")                                                                      \
    for (int kt = 0; kt < 4; ++kt) a0 = mfma16(aS[kt], P##wkA[kt], a0);                    \
    _Pragma("unroll")                                                                      \
    for (int kt = 4; kt < 8; ++kt) a1 = mfma16(aS[kt], P##wkA[kt], a1);                    \
    vnT[team][quad * 4 + 0][c] = f2bf(bf2f(P##vA.x) - a0[0] - a1[0]);                      \
    vnT[team][quad * 4 + 1][c] = f2bf(bf2f(P##vA.y) - a0[1] - a1[1]);                      \
    vnT[team][quad * 4 + 2][c] = f2bf(bf2f(P##vA.z) - a0[2] - a1[2]);                      \
    vnT[team][quad * 4 + 3][c] = f2bf(bf2f(P##vA.w) - a0[3] - a1[3]);                      \
    /* S^T @ rk (needs only aS) + Sacc decay: hoisted above barrier (b), off vnT path */   \
    f32x4 r0 = (f32x4){0.f, 0.f, 0.f, 0.f}, r1 = (f32x4){0.f, 0.f, 0.f, 0.f};              \
    _Pragma("unroll")                                                                      \
    for (int kt = 0; kt < 4; ++kt) r0 = mfma16(aS[kt], P##rk[kt], r0);                     \
    _Pragma("unroll")                                                                      \
    for (int kt = 4; kt < 8; ++kt) r1 = mfma16(aS[kt], P##rk[kt], r1);                     \
    _Pragma("unroll")                                                                      \
    for (int nt = 0; nt < 4; ++nt)                                                         \
      _Pragma("unroll")                                                                    \
      for (int r = 0; r < 4; ++r) Sacc[nt][r] *= gC;                                       \
    KBAR(); /* (b) vnT visible */                                                          \
    bf16x8 aV[2];                                                                          \
    _Pragma("unroll")                                                                      \
    for (int kt = 0; kt < 2; ++kt)                                                         \
      aV[kt] = *reinterpret_cast<const bf16x8*>(&vnT[team][lane15][kt * 32 + quad * 8]);   \
    /* phase C first: S^T := gC*S^T + v_new^T @ wkg (critical path to next barrier) */     \
    _Pragma("unroll")                                                                      \
    for (int nt = 0; nt < 4; ++nt) {                                                       \
      _Pragma("unroll")                                                                    \
      for (int kt = 0; kt < 2; ++kt) Sacc[nt] = mfma16(aV[kt], P##wkg[nt * 2 + kt], Sacc[nt]); \
      _Pragma("unroll")                                                                    \
      for (int r = 0; r < 4; ++r)                                                          \
        STb[team][quad * 4 + r][w * 64 + nt * 16 + lane15] = f2bf(Sacc[nt][r]);            \
    }                                                                                      \
    /* phase B tail: o^T = diag(g^c)*(S^T @ rk^T) + v_new^T @ intra^T, *alpha, store */    \
    {                                                                                      \
      f32x4 i0 = (f32x4){0.f, 0.f, 0.f, 0.f};                                              \
      _Pragma("unroll")                                                                    \
      for (int kt = 0; kt < 2; ++kt) i0 = mfma16(aV[kt], P##in[kt], i0);                   \
      ushort4 ov;                                                                          \
      ov.x = f2bf(((r0[0] + r1[0]) * gc + i0[0]) * alpha);                                 \
      ov.y = f2bf(((r0[1] + r1[1]) * gc + i0[1]) * alpha);                                 \
      ov.z = f2bf(((r0[2] + r1[2]) * gc + i0[2]) * alpha);                                 \
      ov.w = f2bf(((r0[3] + r1[3]) * gc + i0[3]) * alpha);                                 \
      *reinterpret_cast<ushort4*>(&o[((size_t)(b * T_SEQ + (n_) * 64 + c)) * DM + h * HD + j0 + quad * 4]) = ov; \
    }                                                                                      \
  } while (0)

  LOADB(A, 0);
#pragma unroll 1
  for (int n = 0; n < 128; n += 2) {
    STEP(A, B, n, true);            // n+1 <= 127 always valid
    STEP(B, A, n + 1, (n + 2 < 128));
  }
#undef STEP
#undef KBAR
#undef LOADB
}

extern "C" void kernel_launch(void* const* d_in, const int* in_sizes, int n_in,
                              void* d_out, int out_size, void* d_ws, size_t ws_size,
                              hipStream_t stream) {
  const float* x = (const float*)d_in[0];
  const float* Ww = (const float*)d_in[1];
  const float* Wr = (const float*)d_in[2];
  const float* decay = (const float*)d_in[3];
  const float* lalpha = (const float*)d_in[4];

  char* ws = (char*)d_ws;
  size_t off = 0;
  auto alloc = [&](size_t bytes) {
    char* p = ws + off;
    off += (bytes + 255) & ~(size_t)255;
    return p;
  };
  u16* xb16 = (u16*)alloc(33554432);   // (B,T,D) bf16 x   (later aliased as o)
  u16* rk16 = (u16*)alloc(33554432);   // (B,T,D) bf16 rk
  u16* v16  = (u16*)alloc(33554432);   // (B,T,D) bf16 v
  u16* vAb  = (u16*)alloc(33554432);   // (BH,N,C,d)
  u16* wkAb = (u16*)alloc(33554432);   // (BH,N,C,d)
  u16* wkgb = (u16*)alloc(33554432);   // (BH,N,d,C)
  u16* intrb = (u16*)alloc(8388608);   // (BH,N,C,C)
  u16* Ww16 = (u16*)alloc(2097152);
  u16* Wr16 = (u16*)alloc(2097152);
  u16* o16 = xb16;  // alias: xb16 dead after GEMM1

  kconv<<<1024, 256, 0, stream>>>(Ww, Ww16, 262144);
  kconv<<<1024, 256, 0, stream>>>(Wr, Wr16, 262144);
  k_rk<<<16384, 256, 0, stream>>>(x, xb16, rk16);
  gemm_bt<true><<<1024, 256, 0, stream>>>(xb16, Ww16, v16, nullptr, nullptr, 16384, 1024, 1024);
  k2<<<1024, 256, 0, stream>>>(rk16, v16, vAb, wkAb, wkgb, intrb, decay);
  k3<<<64, 512, 0, stream>>>(rk16, vAb, wkAb, wkgb, intrb, decay, lalpha, o16);
  gemm_bt<false><<<1024, 256, 0, stream>>>(o16, Wr16, nullptr, (float*)d_out, x, 16384, 1024, 1024);
}

// Round 4
// 752.499 us; speedup vs baseline: 2.0636x; 2.0636x over previous
//
#include <hip/hip_runtime.h>
#include <stdint.h>

typedef unsigned short u16;
typedef unsigned int u32;
typedef __attribute__((ext_vector_type(8))) short bf16x8;
typedef __attribute__((ext_vector_type(4))) float f32x4;

#define T_SEQ 8192
#define DM 1024
#define HD 256

__device__ __forceinline__ u16 f2bf(float f) {
  u32 u = __float_as_uint(f);
  u32 r = (u + 0x7fffu + ((u >> 16) & 1u)) >> 16;
  return (u16)r;
}
__device__ __forceinline__ float bf2f(u16 u) {
  return __uint_as_float(((u32)u) << 16);
}
__device__ __forceinline__ f32x4 mfma16(bf16x8 a, bf16x8 b, f32x4 c) {
  return __builtin_amdgcn_mfma_f32_16x16x32_bf16(a, b, c, 0, 0, 0);
}
// async global->LDS, 16B per lane. LDS dest must be wave-uniform base + lane*16.
__device__ __forceinline__ void gl2lds16(const u16* g, u16* l) {
  __builtin_amdgcn_global_load_lds(
      (const __attribute__((address_space(1))) u32*)(uintptr_t)g,
      (__attribute__((address_space(3))) u32*)(u32)(uintptr_t)l, 16, 0, 0);
}

// ---------------- fp32 -> bf16 bulk convert ----------------
__global__ __launch_bounds__(256) void kconv(const float* __restrict__ src, u16* __restrict__ dst, int n4) {
  int i = blockIdx.x * 256 + threadIdx.x;
  if (i < n4) {
    float4 v = reinterpret_cast<const float4*>(src)[i];
    ushort4 s;
    s.x = f2bf(v.x); s.y = f2bf(v.y); s.z = f2bf(v.z); s.w = f2bf(v.w);
    reinterpret_cast<ushort4*>(dst)[i] = s;
  }
}

// ---------------- K1: xb16 + per-head-normalized rk (both (B,T,D) bf16) ----------------
__global__ __launch_bounds__(256) void k_rk(const float* __restrict__ x, u16* __restrict__ xb, u16* __restrict__ rk) {
  const int row = blockIdx.x;
  const int t = threadIdx.x;
  const size_t base = (size_t)row * DM + t * 4;
  float4 v = *reinterpret_cast<const float4*>(&x[base]);
  ushort4 s;
  s.x = f2bf(v.x); s.y = f2bf(v.y); s.z = f2bf(v.z); s.w = f2bf(v.w);
  *reinterpret_cast<ushort4*>(&xb[base]) = s;
  float ss = v.x * v.x + v.y * v.y + v.z * v.z + v.w * v.w;
#pragma unroll
  for (int m = 1; m < 64; m <<= 1) ss += __shfl_xor(ss, m, 64);
  float inv = 1.0f / fmaxf(sqrtf(ss), 1e-12f);
  ushort4 r;
  r.x = f2bf(v.x * inv); r.y = f2bf(v.y * inv); r.z = f2bf(v.z * inv); r.w = f2bf(v.w * inv);
  *reinterpret_cast<ushort4*>(&rk[base]) = r;
}

// ---------------- GEMM: C[M,N] = A[M,K] @ Bt[N,K]^T (bf16 in, fp32 acc) ----------------
template <bool STORE_BF16>
__global__ __launch_bounds__(256) void gemm_bt(const u16* __restrict__ A, const u16* __restrict__ Bt,
                                               u16* __restrict__ Cb, float* __restrict__ Cf,
                                               const float* __restrict__ addin, int M, int N, int K) {
  __shared__ __align__(16) u16 As[128 * 64];
  __shared__ __align__(16) u16 Bs[128 * 64];
  const int tiles_n = N >> 7;
  const int tm = (blockIdx.x / tiles_n) << 7;
  const int tn = (blockIdx.x % tiles_n) << 7;
  const int t = threadIdx.x;
  const int w = t >> 6, l = t & 63;
  const int lane15 = l & 15, quad = l >> 4;
  const int wm = w & 1, wn = w >> 1;
  const int r0 = t >> 3;          // 0..31
  const int kc = (t & 7) << 3;    // 0..56 (u16 units, 16B chunks)

  f32x4 acc[4][4];
#pragma unroll
  for (int mi = 0; mi < 4; ++mi)
#pragma unroll
    for (int ni = 0; ni < 4; ++ni) acc[mi][ni] = (f32x4){0.f, 0.f, 0.f, 0.f};

  const int NK = K >> 6;
#pragma unroll 1
  for (int kt = 0; kt < NK; ++kt) {
    __syncthreads();
    const int k0 = kt << 6;
#pragma unroll
    for (int j = 0; j < 4; ++j) {
      gl2lds16(&A[(size_t)(tm + r0 + j * 32) * K + k0 + kc], &As[(r0 + j * 32) * 64 + kc]);
      gl2lds16(&Bt[(size_t)(tn + r0 + j * 32) * K + k0 + kc], &Bs[(r0 + j * 32) * 64 + kc]);
    }
    __syncthreads();
#pragma unroll
    for (int kk = 0; kk < 2; ++kk) {
      bf16x8 af[4], bfr[4];
#pragma unroll
      for (int mi = 0; mi < 4; ++mi)
        af[mi] = *reinterpret_cast<const bf16x8*>(&As[(wm * 64 + mi * 16 + lane15) * 64 + kk * 32 + quad * 8]);
#pragma unroll
      for (int ni = 0; ni < 4; ++ni)
        bfr[ni] = *reinterpret_cast<const bf16x8*>(&Bs[(wn * 64 + ni * 16 + lane15) * 64 + kk * 32 + quad * 8]);
#pragma unroll
      for (int mi = 0; mi < 4; ++mi)
#pragma unroll
        for (int ni = 0; ni < 4; ++ni) acc[mi][ni] = mfma16(af[mi], bfr[ni], acc[mi][ni]);
    }
  }
#pragma unroll
  for (int mi = 0; mi < 4; ++mi)
#pragma unroll
    for (int ni = 0; ni < 4; ++ni)
#pragma unroll
      for (int r = 0; r < 4; ++r) {
        int row = tm + wm * 64 + mi * 16 + quad * 4 + r;
        int col = tn + wn * 64 + ni * 16 + lane15;
        size_t idx = (size_t)row * N + col;
        float vv = acc[mi][ni][r];
        if (STORE_BF16) Cb[idx] = f2bf(vv);
        else Cf[idx] = vv + addin[idx];
      }
}

// ---------------- K2 (MFMA rewrite): per-chunk A0, blocked inv, intra, vA, wkA, wkgT ----------------
// One block per (bh, n) chunk. 256 threads = 4 waves. ~111 KB LDS -> 1 block/CU.
__global__ __launch_bounds__(256, 1) void k2(const u16* __restrict__ rk, const u16* __restrict__ v,
                                             u16* __restrict__ vA, u16* __restrict__ wkA,
                                             u16* __restrict__ wkgT, u16* __restrict__ intra,
                                             const float* __restrict__ decay) {
  __shared__ __align__(16) u16 sk[65][264];     // wk_ext rows (row r = token n*64-1+r), bf16
  __shared__ __align__(16) u16 tT[256][72];     // transposed operand (wkT, then vT)
  __shared__ __align__(16) float Am[64][68];    // A0 (strict lower valid), f32
  __shared__ __align__(16) float Xm[64][68];    // X = inv(I - A0), full explicit
  __shared__ __align__(16) float tmpT[4][16][20];
  __shared__ float gp[65];
  const int bx = blockIdx.x;
  const int bh = bx >> 7, n = bx & 127;
  const int b = bh >> 2, h = bh & 3;
  const int t = threadIdx.x;
  const int w = t >> 6, l = t & 63;
  const int lane15 = l & 15, quad = l >> 4;
  const int li = l & 15, jq = l >> 4;

  if (t <= 64) {
    float gamma = 1.0f / (1.0f + __expf(-decay[h]));
    gp[t] = __powf(gamma, (float)t);
  }
  // zero Am, Xm (incl pad)
  for (int i = t; i < 64 * 68; i += 256) {
    (&Am[0][0])[i] = 0.0f;
    (&Xm[0][0])[i] = 0.0f;
  }
  // stage sk (row-major) + wkT (transposed) from global rk
  for (int i = t; i < 65 * 32; i += 256) {
    const int r = i >> 5, c16 = i & 31;
    const int g = n * 64 - 1 + r;
    uint4 val = make_uint4(0, 0, 0, 0);
    if (g >= 0) val = *reinterpret_cast<const uint4*>(&rk[((size_t)(b * T_SEQ + g)) * DM + h * HD + c16 * 8]);
    *reinterpret_cast<uint4*>(&sk[r][c16 * 8]) = val;
    if (r < 64) {
      u16 e[8];
      e[0] = val.x & 0xffff; e[1] = val.x >> 16;
      e[2] = val.y & 0xffff; e[3] = val.y >> 16;
      e[4] = val.z & 0xffff; e[5] = val.z >> 16;
      e[6] = val.w & 0xffff; e[7] = val.w >> 16;
#pragma unroll
      for (int ee = 0; ee < 8; ++ee) tT[c16 * 8 + ee][r] = e[ee];
    }
  }
  __syncthreads();

  // ---- step 1: M_ww = wk@wk^T (waves 0,1), M_rw = rk@wk^T (waves 2,3) via MFMA ----
  {
    const int prod = w >> 1;          // 0: ww, 1: rw
    const int tib = (w & 1) * 2;      // ti in {tib, tib+1}
    f32x4 s1[2][4];
#pragma unroll
    for (int a = 0; a < 2; ++a)
#pragma unroll
      for (int tj = 0; tj < 4; ++tj) s1[a][tj] = (f32x4){0.f, 0.f, 0.f, 0.f};
#pragma unroll
    for (int ks = 0; ks < 8; ++ks) {
      bf16x8 afr[2], bfr[4];
#pragma unroll
      for (int a = 0; a < 2; ++a)
        afr[a] = *reinterpret_cast<const bf16x8*>(&sk[(tib + a) * 16 + lane15 + prod][ks * 32 + quad * 8]);
#pragma unroll
      for (int tj = 0; tj < 4; ++tj)
        bfr[tj] = *reinterpret_cast<const bf16x8*>(&sk[tj * 16 + lane15][ks * 32 + quad * 8]);
#pragma unroll
      for (int a = 0; a < 2; ++a)
#pragma unroll
        for (int tj = 0; tj < 4; ++tj) s1[a][tj] = mfma16(afr[a], bfr[tj], s1[a][tj]);
    }
    if (prod == 0) {
#pragma unroll
      for (int a = 0; a < 2; ++a)
#pragma unroll
        for (int tj = 0; tj < 4; ++tj)
#pragma unroll
          for (int r = 0; r < 4; ++r) {
            const int i = (tib + a) * 16 + quad * 4 + r, j = tj * 16 + lane15;
            if (j < i) Am[i][j] = -s1[a][tj][r] * gp[i - j];
          }
    } else {
      u16* intra_n = intra + (size_t)bx * 4096;
#pragma unroll
      for (int a = 0; a < 2; ++a)
#pragma unroll
        for (int tj = 0; tj < 4; ++tj)
#pragma unroll
          for (int r = 0; r < 4; ++r) {
            const int i = (tib + a) * 16 + quad * 4 + r, j = tj * 16 + lane15;
            intra_n[i * 64 + j] = (j < i) ? f2bf(s1[a][tj][r] * gp[i - j]) : (u16)0;
          }
    }
  }
  __syncthreads();

  // ---- step 2a: invert diagonal 16x16 blocks (wave w -> block w), column-parallel ----
  if (l < 16) {
    const int bi = w * 16;
    const int j = l;
    Xm[bi + j][bi + j] = 1.0f;
    for (int i = 1; i < 16; ++i) {
      if (j < i) {
        float acc = Am[bi + i][bi + j];
        for (int k = j + 1; k < i; ++k) acc += Am[bi + i][bi + k] * Xm[bi + k][bi + j];
        Xm[bi + i][bi + j] = acc;
      }
    }
  }
  __syncthreads();

  // ---- step 2b: off-diagonal blocks, levels 1..3: X(I,J) = X(I,I) * sum_K A0(I,K) X(K,J) ----
  for (int lvl = 1; lvl < 4; ++lvl) {
    if (w + lvl < 4) {
      const int I = w + lvl, J = w;
      float a4[4] = {0.f, 0.f, 0.f, 0.f};
      for (int K = J; K < I; ++K) {
#pragma unroll
        for (int k = 0; k < 16; ++k) {
          const float a = Am[I * 16 + li][K * 16 + k];
          const float* xr = &Xm[K * 16 + k][J * 16 + jq * 4];
          a4[0] += a * xr[0]; a4[1] += a * xr[1]; a4[2] += a * xr[2]; a4[3] += a * xr[3];
        }
      }
#pragma unroll
      for (int r = 0; r < 4; ++r) tmpT[w][li][jq * 4 + r] = a4[r];
      asm volatile("" ::: "memory");
      float b4[4] = {0.f, 0.f, 0.f, 0.f};
#pragma unroll
      for (int k = 0; k < 16; ++k) {
        const float a = Xm[I * 16 + li][I * 16 + k];
        const float* tr = &tmpT[w][k][jq * 4];
        b4[0] += a * tr[0]; b4[1] += a * tr[1]; b4[2] += a * tr[2]; b4[3] += a * tr[3];
      }
#pragma unroll
      for (int r = 0; r < 4; ++r) Xm[I * 16 + li][J * 16 + jq * 4 + r] = b4[r];
    }
    __syncthreads();
  }

  // ---- step 3: products X @ wk (then X @ v) via MFMA; output (C x d) row-major bf16 ----
  auto product = [&](u16* dst) {
    bf16x8 afr[2];
#pragma unroll
    for (int ks = 0; ks < 2; ++ks) {
      const float* xr = &Xm[w * 16 + lane15][ks * 32 + quad * 8];
      bf16x8 f;
#pragma unroll
      for (int e = 0; e < 8; ++e) ((u16*)&f)[e] = f2bf(xr[e]);
      afr[ks] = f;
    }
#pragma unroll
    for (int nj = 0; nj < 16; ++nj) {
      f32x4 acc = (f32x4){0.f, 0.f, 0.f, 0.f};
#pragma unroll
      for (int ks = 0; ks < 2; ++ks) {
        bf16x8 bfr = *reinterpret_cast<const bf16x8*>(&tT[nj * 16 + lane15][ks * 32 + quad * 8]);
        acc = mfma16(afr[ks], bfr, acc);
      }
#pragma unroll
      for (int r = 0; r < 4; ++r)
        dst[(size_t)(w * 16 + quad * 4 + r) * 256 + nj * 16 + lane15] = f2bf(acc[r]);
    }
  };
  product(wkA + (size_t)bx * (64 * 256));
  // wkgT[i][c] = wk[c][i] * gamma^(63-c) = wkT[i][c] * gp[63-c], layout (d, C)
  {
    u16* wkg_n = wkgT + (size_t)bx * (256 * 64);
    const int i = t;
#pragma unroll
    for (int c16 = 0; c16 < 8; ++c16) {
      bf16x8 rv = *reinterpret_cast<const bf16x8*>(&tT[i][c16 * 8]);
      bf16x8 ov;
#pragma unroll
      for (int e = 0; e < 8; ++e)
        ((u16*)&ov)[e] = f2bf(bf2f(((u16*)&rv)[e]) * gp[63 - (c16 * 8 + e)]);
      *reinterpret_cast<bf16x8*>(&wkg_n[i * 64 + c16 * 8]) = ov;
    }
  }
  __syncthreads();  // all tT (wkT) reads done
  // stage vT
  for (int i = t; i < 64 * 32; i += 256) {
    const int r = i >> 5, c16 = i & 31;
    uint4 val = *reinterpret_cast<const uint4*>(&v[((size_t)(b * T_SEQ + n * 64 + r)) * DM + h * HD + c16 * 8]);
    u16 e[8];
    e[0] = val.x & 0xffff; e[1] = val.x >> 16;
    e[2] = val.y & 0xffff; e[3] = val.y >> 16;
    e[4] = val.z & 0xffff; e[5] = val.z >> 16;
    e[6] = val.w & 0xffff; e[7] = val.w >> 16;
#pragma unroll
    for (int ee = 0; ee < 8; ++ee) tT[c16 * 8 + ee][r] = e[ee];
  }
  __syncthreads();
  product(vA + (size_t)bx * (64 * 256));
}

// ---------------- K3: sequential scan; XCD-swizzled; distance-1 register double-buffer ----------------
// Round-1 structure (256 thr, grid 128, full register dbuf, VGPR ~168, no spill) with ONE change:
// KBAR uses compiler-modeled builtins (s_waitcnt lgkmcnt(0) imm=0xC07F + s_barrier) instead of
// inline asm with a "memory" clobber. The clobber forced the memory legalizer to conservatively
// drain vmcnt(0) at every barrier, killing the prefetch (round-1 only gained 473->391). Builtins
// carry no memory clobber -> counted vmcnt waits survive the barrier and prefetch stays in flight.
__global__ __launch_bounds__(256, 1) void k3(const u16* __restrict__ rk, const u16* __restrict__ vA,
                                             const u16* __restrict__ wkA, const u16* __restrict__ wkgT,
                                             const u16* __restrict__ intra, const float* __restrict__ decay,
                                             const float* __restrict__ log_alpha, u16* __restrict__ o) {
  __shared__ __align__(16) u16 STb[16][264];   // S^T bf16 copy: [jl][i], padded
  __shared__ __align__(16) u16 vnT[16][72];    // v_new^T [jl][c]
  // XCD swizzle: all 16 column-block WGs of one bh land on the same XCD (round-robin dispatch)
  const int bh = blockIdx.x & 7, jb = blockIdx.x >> 3;
  const int b = bh >> 2, h = bh & 3;
  const int j0 = jb << 4;
  const int t = threadIdx.x, w = t >> 6, l = t & 63;
  const int lane15 = l & 15, quad = l >> 4;
  const float gamma = 1.0f / (1.0f + __expf(-decay[h]));
  const float alpha = __expf(log_alpha[h]);
  const float gC = __powf(gamma, 64.0f);
  const int c = w * 16 + lane15;               // chunk-row this lane owns in phases A/B
  const float gc = __powf(gamma, (float)c);
  for (int i = t; i < 2112; i += 256) reinterpret_cast<u32*>(&STb[0][0])[i] = 0u;
  f32x4 Sacc[4];
#pragma unroll
  for (int nt = 0; nt < 4; ++nt) Sacc[nt] = (f32x4){0.f, 0.f, 0.f, 0.f};

  const size_t chb = (size_t)bh * 128;
  const u16* wkA_b = wkA + chb * (64 * 256);
  const u16* vA_b = vA + chb * (64 * 256);
  const u16* wkg_b = wkgT + chb * (256 * 64);
  const u16* intr_b = intra + chb * 4096;
  const u16* rk_b = rk + ((size_t)(b * T_SEQ)) * DM + h * HD;

  // Double-buffered per-step register staging (token-pasted names; all indices compile-time).
  bf16x8 AwkA[8], Ark[8], Awkg[8], Ain[2]; ushort4 AvA;
  bf16x8 BwkA[8], Brk[8], Bwkg[8], Bin[2]; ushort4 BvA;

  // Loads ordered by first use: wkA (phase A) -> vA -> rk (A2) -> intra (B) -> wkg (C).
#define LOADB(P, n_) do {                                                                  \
    const u16* wkA_n = wkA_b + (size_t)(n_) * (64 * 256);                                  \
    const u16* vA_n = vA_b + (size_t)(n_) * (64 * 256);                                    \
    const u16* wkg_n = wkg_b + (size_t)(n_) * (256 * 64);                                  \
    const u16* intr_n = intr_b + (size_t)(n_) * 4096;                                      \
    const u16* rk_n = rk_b + (size_t)(n_) * 64 * DM;                                       \
    const u16* wrow = wkA_n + c * 256 + quad * 8;                                          \
    _Pragma("unroll")                                                                      \
    for (int kt = 0; kt < 8; ++kt) P##wkA[kt] = *reinterpret_cast<const bf16x8*>(&wrow[kt * 32]); \
    P##vA = *reinterpret_cast<const ushort4*>(&vA_n[c * 256 + j0 + quad * 4]);             \
    const u16* rrow = rk_n + (size_t)c * DM + quad * 8;                                    \
    _Pragma("unroll")                                                                      \
    for (int kt = 0; kt < 8; ++kt) P##rk[kt] = *reinterpret_cast<const bf16x8*>(&rrow[kt * 32]); \
    const u16* irow = intr_n + c * 64 + quad * 8;                                          \
    _Pragma("unroll")                                                                      \
    for (int kt = 0; kt < 2; ++kt) P##in[kt] = *reinterpret_cast<const bf16x8*>(&irow[kt * 32]); \
    _Pragma("unroll")                                                                      \
    for (int nt = 0; nt < 4; ++nt)                                                         \
      _Pragma("unroll")                                                                    \
      for (int kt = 0; kt < 2; ++kt)                                                       \
        P##wkg[nt * 2 + kt] =                                                              \
            *reinterpret_cast<const bf16x8*>(&wkg_n[(size_t)(w * 64 + nt * 16 + lane15) * 64 + kt * 32 + quad * 8]); \
  } while (0)

  // Raw barrier via compiler-modeled builtins only (NO asm, NO memory clobber):
  //   s_waitcnt imm 0xC07F = vmcnt(max) expcnt(max) lgkmcnt(0)  -> own LDS writes complete
  //   s_barrier                                                  -> cross-wave visibility
  //   sched_barrier(0)                                           -> pin scheduler (rule #18)
#define KBAR() do {                                              \
    __builtin_amdgcn_s_waitcnt(0xC07F);                          \
    __builtin_amdgcn_s_barrier();                                \
    __builtin_amdgcn_sched_barrier(0);                           \
  } while (0)

#define STEP(P, Q, n_, do_pf) do {                                                         \
    if (do_pf) LOADB(Q, (n_) + 1); /* issue next step's loads before waiting */            \
    KBAR(); /* (a) STb from prev phase C visible */                                        \
    bf16x8 aS[8];                                                                          \
    _Pragma("unroll")                                                                      \
    for (int kt = 0; kt < 8; ++kt)                                                         \
      aS[kt] = *reinterpret_cast<const bf16x8*>(&STb[lane15][kt * 32 + quad * 8]);         \
    /* phase A: P^T = S^T @ wkA^T (2 parallel 4-chains); v_new^T = vA^T - P^T */           \
    f32x4 a0 = (f32x4){0.f, 0.f, 0.f, 0.f}, a1 = (f32x4){0.f, 0.f, 0.f, 0.f};              \
    _Pragma("unroll")                                                                      \
    for (int kt = 0; kt < 4; ++kt) a0 = mfma16(aS[kt], P##wkA[kt], a0);                    \
    _Pragma("unroll")                                                                      \
    for (int kt = 4; kt < 8; ++kt) a1 = mfma16(aS[kt], P##wkA[kt], a1);                    \
    vnT[quad * 4 + 0][c] = f2bf(bf2f(P##vA.x) - a0[0] - a1[0]);                            \
    vnT[quad * 4 + 1][c] = f2bf(bf2f(P##vA.y) - a0[1] - a1[1]);                            \
    vnT[quad * 4 + 2][c] = f2bf(bf2f(P##vA.z) - a0[2] - a1[2]);                            \
    vnT[quad * 4 + 3][c] = f2bf(bf2f(P##vA.w) - a0[3] - a1[3]);                            \
    /* S^T @ rk (needs only aS) + Sacc decay: hoisted above barrier (b), off vnT path */   \
    f32x4 r0 = (f32x4){0.f, 0.f, 0.f, 0.f}, r1 = (f32x4){0.f, 0.f, 0.f, 0.f};              \
    _Pragma("unroll")                                                                      \
    for (int kt = 0; kt < 4; ++kt) r0 = mfma16(aS[kt], P##rk[kt], r0);                     \
    _Pragma("unroll")                                                                      \
    for (int kt = 4; kt < 8; ++kt) r1 = mfma16(aS[kt], P##rk[kt], r1);                     \
    _Pragma("unroll")                                                                      \
    for (int nt = 0; nt < 4; ++nt)                                                         \
      _Pragma("unroll")                                                                    \
      for (int r = 0; r < 4; ++r) Sacc[nt][r] *= gC;                                       \
    KBAR(); /* (b) vnT visible */                                                          \
    bf16x8 aV[2];                                                                          \
    _Pragma("unroll")                                                                      \
    for (int kt = 0; kt < 2; ++kt)                                                         \
      aV[kt] = *reinterpret_cast<const bf16x8*>(&vnT[lane15][kt * 32 + quad * 8]);         \
    /* phase C first: S^T := gC*S^T + v_new^T @ wkg (critical path to next barrier) */     \
    _Pragma("unroll")                                                                      \
    for (int nt = 0; nt < 4; ++nt) {                                                       \
      _Pragma("unroll")                                                                    \
      for (int kt = 0; kt < 2; ++kt) Sacc[nt] = mfma16(aV[kt], P##wkg[nt * 2 + kt], Sacc[nt]); \
      _Pragma("unroll")                                                                    \
      for (int r = 0; r < 4; ++r)                                                          \
        STb[quad * 4 + r][w * 64 + nt * 16 + lane15] = f2bf(Sacc[nt][r]);                  \
    }                                                                                      \
    /* phase B tail: o^T = diag(g^c)*(S^T @ rk^T) + v_new^T @ intra^T, *alpha, store */    \
    {                                                                                      \
      f32x4 i0 = (f32x4){0.f, 0.f, 0.f, 0.f};                                              \
      _Pragma("unroll")                                                                    \
      for (int kt = 0; kt < 2; ++kt) i0 = mfma16(aV[kt], P##in[kt], i0);                   \
      ushort4 ov;                                                                          \
      ov.x = f2bf(((r0[0] + r1[0]) * gc + i0[0]) * alpha);                                 \
      ov.y = f2bf(((r0[1] + r1[1]) * gc + i0[1]) * alpha);                                 \
      ov.z = f2bf(((r0[2] + r1[2]) * gc + i0[2]) * alpha);                                 \
      ov.w = f2bf(((r0[3] + r1[3]) * gc + i0[3]) * alpha);                                 \
      *reinterpret_cast<ushort4*>(&o[((size_t)(b * T_SEQ + (n_) * 64 + c)) * DM + h * HD + j0 + quad * 4]) = ov; \
    }                                                                                      \
  } while (0)

  LOADB(A, 0);
#pragma unroll 1
  for (int n = 0; n < 128; n += 2) {
    STEP(A, B, n, true);            // n+1 <= 127 always valid
    STEP(B, A, n + 1, (n + 2 < 128));
  }
#undef STEP
#undef KBAR
#undef LOADB
}

extern "C" void kernel_launch(void* const* d_in, const int* in_sizes, int n_in,
                              void* d_out, int out_size, void* d_ws, size_t ws_size,
                              hipStream_t stream) {
  const float* x = (const float*)d_in[0];
  const float* Ww = (const float*)d_in[1];
  const float* Wr = (const float*)d_in[2];
  const float* decay = (const float*)d_in[3];
  const float* lalpha = (const float*)d_in[4];

  char* ws = (char*)d_ws;
  size_t off = 0;
  auto alloc = [&](size_t bytes) {
    char* p = ws + off;
    off += (bytes + 255) & ~(size_t)255;
    return p;
  };
  u16* xb16 = (u16*)alloc(33554432);   // (B,T,D) bf16 x   (later aliased as o)
  u16* rk16 = (u16*)alloc(33554432);   // (B,T,D) bf16 rk
  u16* v16  = (u16*)alloc(33554432);   // (B,T,D) bf16 v
  u16* vAb  = (u16*)alloc(33554432);   // (BH,N,C,d)
  u16* wkAb = (u16*)alloc(33554432);   // (BH,N,C,d)
  u16* wkgb = (u16*)alloc(33554432);   // (BH,N,d,C)
  u16* intrb = (u16*)alloc(8388608);   // (BH,N,C,C)
  u16* Ww16 = (u16*)alloc(2097152);
  u16* Wr16 = (u16*)alloc(2097152);
  u16* o16 = xb16;  // alias: xb16 dead after GEMM1

  kconv<<<1024, 256, 0, stream>>>(Ww, Ww16, 262144);
  kconv<<<1024, 256, 0, stream>>>(Wr, Wr16, 262144);
  k_rk<<<16384, 256, 0, stream>>>(x, xb16, rk16);
  gemm_bt<true><<<1024, 256, 0, stream>>>(xb16, Ww16, v16, nullptr, nullptr, 16384, 1024, 1024);
  k2<<<1024, 256, 0, stream>>>(rk16, v16, vAb, wkAb, wkgb, intrb, decay);
  k3<<<128, 256, 0, stream>>>(rk16, vAb, wkAb, wkgb, intrb, decay, lalpha, o16);
  gemm_bt<false><<<1024, 256, 0, stream>>>(o16, Wr16, nullptr, (float*)d_out, x, 16384, 1024, 1024);
}

// Round 6
// 590.067 us; speedup vs baseline: 2.6316x; 1.2753x over previous
//
#include <hip/hip_runtime.h>
#include <stdint.h>

typedef unsigned short u16;
typedef unsigned int u32;
typedef __attribute__((ext_vector_type(8))) short bf16x8;
typedef __attribute__((ext_vector_type(4))) float f32x4;

#define T_SEQ 8192
#define DM 1024
#define HD 256

__device__ __forceinline__ u16 f2bf(float f) {
  u32 u = __float_as_uint(f);
  u32 r = (u + 0x7fffu + ((u >> 16) & 1u)) >> 16;
  return (u16)r;
}
__device__ __forceinline__ float bf2f(u16 u) {
  return __uint_as_float(((u32)u) << 16);
}
__device__ __forceinline__ f32x4 mfma16(bf16x8 a, bf16x8 b, f32x4 c) {
  return __builtin_amdgcn_mfma_f32_16x16x32_bf16(a, b, c, 0, 0, 0);
}
// async global->LDS, 16B per lane. LDS dest must be wave-uniform base + lane*16.
__device__ __forceinline__ void gl2lds16(const u16* g, u16* l) {
  __builtin_amdgcn_global_load_lds(
      (const __attribute__((address_space(1))) u32*)(uintptr_t)g,
      (__attribute__((address_space(3))) u32*)(u32)(uintptr_t)l, 16, 0, 0);
}

// ---------------- fp32 -> bf16 bulk convert ----------------
__global__ __launch_bounds__(256) void kconv(const float* __restrict__ src, u16* __restrict__ dst, int n4) {
  int i = blockIdx.x * 256 + threadIdx.x;
  if (i < n4) {
    float4 v = reinterpret_cast<const float4*>(src)[i];
    ushort4 s;
    s.x = f2bf(v.x); s.y = f2bf(v.y); s.z = f2bf(v.z); s.w = f2bf(v.w);
    reinterpret_cast<ushort4*>(dst)[i] = s;
  }
}

// ---------------- K1: xb16 + per-head-normalized rk (both (B,T,D) bf16) ----------------
__global__ __launch_bounds__(256) void k_rk(const float* __restrict__ x, u16* __restrict__ xb, u16* __restrict__ rk) {
  const int row = blockIdx.x;
  const int t = threadIdx.x;
  const size_t base = (size_t)row * DM + t * 4;
  float4 v = *reinterpret_cast<const float4*>(&x[base]);
  ushort4 s;
  s.x = f2bf(v.x); s.y = f2bf(v.y); s.z = f2bf(v.z); s.w = f2bf(v.w);
  *reinterpret_cast<ushort4*>(&xb[base]) = s;
  float ss = v.x * v.x + v.y * v.y + v.z * v.z + v.w * v.w;
#pragma unroll
  for (int m = 1; m < 64; m <<= 1) ss += __shfl_xor(ss, m, 64);
  float inv = 1.0f / fmaxf(sqrtf(ss), 1e-12f);
  ushort4 r;
  r.x = f2bf(v.x * inv); r.y = f2bf(v.y * inv); r.z = f2bf(v.z * inv); r.w = f2bf(v.w * inv);
  *reinterpret_cast<ushort4*>(&rk[base]) = r;
}

// ---------------- GEMM: C[M,N] = A[M,K] @ Bt[N,K]^T (bf16 in, fp32 acc) ----------------
template <bool STORE_BF16>
__global__ __launch_bounds__(256) void gemm_bt(const u16* __restrict__ A, const u16* __restrict__ Bt,
                                               u16* __restrict__ Cb, float* __restrict__ Cf,
                                               const float* __restrict__ addin, int M, int N, int K) {
  __shared__ __align__(16) u16 As[128 * 64];
  __shared__ __align__(16) u16 Bs[128 * 64];
  const int tiles_n = N >> 7;
  const int tm = (blockIdx.x / tiles_n) << 7;
  const int tn = (blockIdx.x % tiles_n) << 7;
  const int t = threadIdx.x;
  const int w = t >> 6, l = t & 63;
  const int lane15 = l & 15, quad = l >> 4;
  const int wm = w & 1, wn = w >> 1;
  const int r0 = t >> 3;          // 0..31
  const int kc = (t & 7) << 3;    // 0..56 (u16 units, 16B chunks)

  f32x4 acc[4][4];
#pragma unroll
  for (int mi = 0; mi < 4; ++mi)
#pragma unroll
    for (int ni = 0; ni < 4; ++ni) acc[mi][ni] = (f32x4){0.f, 0.f, 0.f, 0.f};

  const int NK = K >> 6;
#pragma unroll 1
  for (int kt = 0; kt < NK; ++kt) {
    __syncthreads();
    const int k0 = kt << 6;
#pragma unroll
    for (int j = 0; j < 4; ++j) {
      gl2lds16(&A[(size_t)(tm + r0 + j * 32) * K + k0 + kc], &As[(r0 + j * 32) * 64 + kc]);
      gl2lds16(&Bt[(size_t)(tn + r0 + j * 32) * K + k0 + kc], &Bs[(r0 + j * 32) * 64 + kc]);
    }
    __syncthreads();
#pragma unroll
    for (int kk = 0; kk < 2; ++kk) {
      bf16x8 af[4], bfr[4];
#pragma unroll
      for (int mi = 0; mi < 4; ++mi)
        af[mi] = *reinterpret_cast<const bf16x8*>(&As[(wm * 64 + mi * 16 + lane15) * 64 + kk * 32 + quad * 8]);
#pragma unroll
      for (int ni = 0; ni < 4; ++ni)
        bfr[ni] = *reinterpret_cast<const bf16x8*>(&Bs[(wn * 64 + ni * 16 + lane15) * 64 + kk * 32 + quad * 8]);
#pragma unroll
      for (int mi = 0; mi < 4; ++mi)
#pragma unroll
        for (int ni = 0; ni < 4; ++ni) acc[mi][ni] = mfma16(af[mi], bfr[ni], acc[mi][ni]);
    }
  }
#pragma unroll
  for (int mi = 0; mi < 4; ++mi)
#pragma unroll
    for (int ni = 0; ni < 4; ++ni)
#pragma unroll
      for (int r = 0; r < 4; ++r) {
        int row = tm + wm * 64 + mi * 16 + quad * 4 + r;
        int col = tn + wn * 64 + ni * 16 + lane15;
        size_t idx = (size_t)row * N + col;
        float vv = acc[mi][ni][r];
        if (STORE_BF16) Cb[idx] = f2bf(vv);
        else Cf[idx] = vv + addin[idx];
      }
}

// ---------------- K2: per-chunk A0, blocked inv, intra, vA, wkA, wkgT ----------------
// Outputs FRAGMENT-MAJOR so k3's register loads are contiguous full-line 1KB bursts:
//   wkAF   : idx = (j>>5)*2048 + (i>>4)*512 + ((j>>3)&3)*128 + (i&15)*8 + (j&7)   (16384 u16/chunk)
//   vAF    : idx = (j>>4)*1024 + (i>>4)*256 + ((j>>2)&3)*64 + (i&15)*4 + (j&3)    (16384 u16/chunk)
//   wkgF   : idx = (i>>6)*4096 + ((i>>4)&3)*1024 + (c>>5)*512 + ((c>>3)&3)*128 + (i&15)*8 + (c&7)
//   intraF : idx = (i>>4)*1024 + (j>>5)*512 + ((j>>3)&3)*128 + (i&15)*8 + (j&7)   (4096 u16/chunk)
__global__ __launch_bounds__(256, 1) void k2(const u16* __restrict__ rk, const u16* __restrict__ v,
                                             u16* __restrict__ vA, u16* __restrict__ wkA,
                                             u16* __restrict__ wkgT, u16* __restrict__ intra,
                                             const float* __restrict__ decay) {
  __shared__ __align__(16) u16 sk[65][264];     // wk_ext rows (row r = token n*64-1+r), bf16
  __shared__ __align__(16) u16 tT[256][72];     // transposed operand (wkT, then vT)
  __shared__ __align__(16) float Am[64][68];    // A0 (strict lower valid), f32
  __shared__ __align__(16) float Xm[64][68];    // X = inv(I - A0), full explicit
  __shared__ __align__(16) float tmpT[4][16][20];
  __shared__ float gp[65];
  const int bx = blockIdx.x;
  const int bh = bx >> 7, n = bx & 127;
  const int b = bh >> 2, h = bh & 3;
  const int t = threadIdx.x;
  const int w = t >> 6, l = t & 63;
  const int lane15 = l & 15, quad = l >> 4;
  const int li = l & 15, jq = l >> 4;

  if (t <= 64) {
    float gamma = 1.0f / (1.0f + __expf(-decay[h]));
    gp[t] = __powf(gamma, (float)t);
  }
  // zero Am, Xm (incl pad)
  for (int i = t; i < 64 * 68; i += 256) {
    (&Am[0][0])[i] = 0.0f;
    (&Xm[0][0])[i] = 0.0f;
  }
  // stage sk (row-major) + wkT (transposed) from global rk
  for (int i = t; i < 65 * 32; i += 256) {
    const int r = i >> 5, c16 = i & 31;
    const int g = n * 64 - 1 + r;
    uint4 val = make_uint4(0, 0, 0, 0);
    if (g >= 0) val = *reinterpret_cast<const uint4*>(&rk[((size_t)(b * T_SEQ + g)) * DM + h * HD + c16 * 8]);
    *reinterpret_cast<uint4*>(&sk[r][c16 * 8]) = val;
    if (r < 64) {
      u16 e[8];
      e[0] = val.x & 0xffff; e[1] = val.x >> 16;
      e[2] = val.y & 0xffff; e[3] = val.y >> 16;
      e[4] = val.z & 0xffff; e[5] = val.z >> 16;
      e[6] = val.w & 0xffff; e[7] = val.w >> 16;
#pragma unroll
      for (int ee = 0; ee < 8; ++ee) tT[c16 * 8 + ee][r] = e[ee];
    }
  }
  __syncthreads();

  // ---- step 1: M_ww = wk@wk^T (waves 0,1), M_rw = rk@wk^T (waves 2,3) via MFMA ----
  {
    const int prod = w >> 1;          // 0: ww, 1: rw
    const int tib = (w & 1) * 2;      // ti in {tib, tib+1}
    f32x4 s1[2][4];
#pragma unroll
    for (int a = 0; a < 2; ++a)
#pragma unroll
      for (int tj = 0; tj < 4; ++tj) s1[a][tj] = (f32x4){0.f, 0.f, 0.f, 0.f};
#pragma unroll
    for (int ks = 0; ks < 8; ++ks) {
      bf16x8 afr[2], bfr[4];
#pragma unroll
      for (int a = 0; a < 2; ++a)
        afr[a] = *reinterpret_cast<const bf16x8*>(&sk[(tib + a) * 16 + lane15 + prod][ks * 32 + quad * 8]);
#pragma unroll
      for (int tj = 0; tj < 4; ++tj)
        bfr[tj] = *reinterpret_cast<const bf16x8*>(&sk[tj * 16 + lane15][ks * 32 + quad * 8]);
#pragma unroll
      for (int a = 0; a < 2; ++a)
#pragma unroll
        for (int tj = 0; tj < 4; ++tj) s1[a][tj] = mfma16(afr[a], bfr[tj], s1[a][tj]);
    }
    if (prod == 0) {
#pragma unroll
      for (int a = 0; a < 2; ++a)
#pragma unroll
        for (int tj = 0; tj < 4; ++tj)
#pragma unroll
          for (int r = 0; r < 4; ++r) {
            const int i = (tib + a) * 16 + quad * 4 + r, j = tj * 16 + lane15;
            if (j < i) Am[i][j] = -s1[a][tj][r] * gp[i - j];
          }
    } else {
      u16* intra_n = intra + (size_t)bx * 4096;
#pragma unroll
      for (int a = 0; a < 2; ++a)
#pragma unroll
        for (int tj = 0; tj < 4; ++tj)
#pragma unroll
          for (int r = 0; r < 4; ++r) {
            const int i = (tib + a) * 16 + quad * 4 + r, j = tj * 16 + lane15;
            const u16 vv = (j < i) ? f2bf(s1[a][tj][r] * gp[i - j]) : (u16)0;
            intra_n[(i >> 4) * 1024 + (j >> 5) * 512 + ((j >> 3) & 3) * 128 + (i & 15) * 8 + (j & 7)] = vv;
          }
    }
  }
  __syncthreads();

  // ---- step 2a: invert diagonal 16x16 blocks (wave w -> block w), column-parallel ----
  if (l < 16) {
    const int bi = w * 16;
    const int j = l;
    Xm[bi + j][bi + j] = 1.0f;
    for (int i = 1; i < 16; ++i) {
      if (j < i) {
        float acc = Am[bi + i][bi + j];
        for (int k = j + 1; k < i; ++k) acc += Am[bi + i][bi + k] * Xm[bi + k][bi + j];
        Xm[bi + i][bi + j] = acc;
      }
    }
  }
  __syncthreads();

  // ---- step 2b: off-diagonal blocks, levels 1..3: X(I,J) = X(I,I) * sum_K A0(I,K) X(K,J) ----
  for (int lvl = 1; lvl < 4; ++lvl) {
    if (w + lvl < 4) {
      const int I = w + lvl, J = w;
      float a4[4] = {0.f, 0.f, 0.f, 0.f};
      for (int K = J; K < I; ++K) {
#pragma unroll
        for (int k = 0; k < 16; ++k) {
          const float a = Am[I * 16 + li][K * 16 + k];
          const float* xr = &Xm[K * 16 + k][J * 16 + jq * 4];
          a4[0] += a * xr[0]; a4[1] += a * xr[1]; a4[2] += a * xr[2]; a4[3] += a * xr[3];
        }
      }
#pragma unroll
      for (int r = 0; r < 4; ++r) tmpT[w][li][jq * 4 + r] = a4[r];
      asm volatile("" ::: "memory");
      float b4[4] = {0.f, 0.f, 0.f, 0.f};
#pragma unroll
      for (int k = 0; k < 16; ++k) {
        const float a = Xm[I * 16 + li][I * 16 + k];
        const float* tr = &tmpT[w][k][jq * 4];
        b4[0] += a * tr[0]; b4[1] += a * tr[1]; b4[2] += a * tr[2]; b4[3] += a * tr[3];
      }
#pragma unroll
      for (int r = 0; r < 4; ++r) Xm[I * 16 + li][J * 16 + jq * 4 + r] = b4[r];
    }
    __syncthreads();
  }

  // ---- step 3: products X @ wk (then X @ v) via MFMA; fragment-major stores ----
  // output element (i = C-row, j = d-col) -> dst[map(i,j)]
  auto product = [&](u16* dst, auto map) {
    bf16x8 afr[2];
#pragma unroll
    for (int ks = 0; ks < 2; ++ks) {
      const float* xr = &Xm[w * 16 + lane15][ks * 32 + quad * 8];
      bf16x8 f;
#pragma unroll
      for (int e = 0; e < 8; ++e) ((u16*)&f)[e] = f2bf(xr[e]);
      afr[ks] = f;
    }
#pragma unroll
    for (int nj = 0; nj < 16; ++nj) {
      f32x4 acc = (f32x4){0.f, 0.f, 0.f, 0.f};
#pragma unroll
      for (int ks = 0; ks < 2; ++ks) {
        bf16x8 bfr = *reinterpret_cast<const bf16x8*>(&tT[nj * 16 + lane15][ks * 32 + quad * 8]);
        acc = mfma16(afr[ks], bfr, acc);
      }
#pragma unroll
      for (int r = 0; r < 4; ++r) {
        const int i = w * 16 + quad * 4 + r, j = nj * 16 + lane15;
        dst[map(i, j)] = f2bf(acc[r]);
      }
    }
  };
  auto map_wkA = [](int i, int j) {
    return (j >> 5) * 2048 + (i >> 4) * 512 + ((j >> 3) & 3) * 128 + (i & 15) * 8 + (j & 7);
  };
  auto map_vA = [](int i, int j) {
    return (j >> 4) * 1024 + (i >> 4) * 256 + ((j >> 2) & 3) * 64 + (i & 15) * 4 + (j & 3);
  };
  product(wkA + (size_t)bx * 16384, map_wkA);
  // wkgF[i][c] = wk[c][i] * gamma^(63-c), fragment-major
  {
    u16* wkg_n = wkgT + (size_t)bx * 16384;
    const int i = t;
#pragma unroll
    for (int c16 = 0; c16 < 8; ++c16) {
      bf16x8 rv = *reinterpret_cast<const bf16x8*>(&tT[i][c16 * 8]);
      bf16x8 ov;
#pragma unroll
      for (int e = 0; e < 8; ++e)
        ((u16*)&ov)[e] = f2bf(bf2f(((u16*)&rv)[e]) * gp[63 - (c16 * 8 + e)]);
      *reinterpret_cast<bf16x8*>(
          &wkg_n[(i >> 6) * 4096 + ((i >> 4) & 3) * 1024 + (c16 >> 2) * 512 + (c16 & 3) * 128 + (i & 15) * 8]) = ov;
    }
  }
  __syncthreads();  // all tT (wkT) reads done
  // stage vT
  for (int i = t; i < 64 * 32; i += 256) {
    const int r = i >> 5, c16 = i & 31;
    uint4 val = *reinterpret_cast<const uint4*>(&v[((size_t)(b * T_SEQ + n * 64 + r)) * DM + h * HD + c16 * 8]);
    u16 e[8];
    e[0] = val.x & 0xffff; e[1] = val.x >> 16;
    e[2] = val.y & 0xffff; e[3] = val.y >> 16;
    e[4] = val.z & 0xffff; e[5] = val.z >> 16;
    e[6] = val.w & 0xffff; e[7] = val.w >> 16;
#pragma unroll
    for (int ee = 0; ee < 8; ++ee) tT[c16 * 8 + ee][r] = e[ee];
  }
  __syncthreads();
  product(vA + (size_t)bx * 16384, map_vA);
}

// ---------------- krkF: fragment-major dense rk copy (written into dead v16 storage) ----------------
// Runs AFTER k2 (stream-ordered): v16's contents are consumed by k2, so its 32MB is reused.
__global__ __launch_bounds__(256) void krkF(const u16* __restrict__ rk, u16* __restrict__ rkF) {
  const int bx = blockIdx.x;           // bh*128 + n
  const int bh = bx >> 7, n = bx & 127;
  const int b = bh >> 2, h = bh & 3;
  u16* rkF_n = rkF + (size_t)bx * 16384;
  const int t = threadIdx.x;
  for (int idx = t; idx < 2048; idx += 256) {
    const int c = idx >> 5, c8 = idx & 31;   // row c (0..63), 8-elem chunk c8 (col = c8*8)
    uint4 val = *reinterpret_cast<const uint4*>(&rk[((size_t)(b * T_SEQ + n * 64 + c)) * DM + h * HD + c8 * 8]);
    *reinterpret_cast<uint4*>(&rkF_n[(c8 >> 2) * 2048 + (c >> 4) * 512 + (c8 & 3) * 128 + (c & 15) * 8]) = val;
  }
}

// ---------------- K3: sequential scan; XCD-swizzled; distance-1 register double-buffer ----------------
// All 27 per-step loads are CONTIGUOUS 1KB full-line bursts (fragment-major operands):
// line-requests per CU-step drop ~1728 -> ~850, attacking the per-CU miss-throughput floor.
__global__ __launch_bounds__(256, 1) void k3(const u16* __restrict__ rkF, const u16* __restrict__ vA,
                                             const u16* __restrict__ wkA, const u16* __restrict__ wkgT,
                                             const u16* __restrict__ intra, const float* __restrict__ decay,
                                             const float* __restrict__ log_alpha, u16* __restrict__ o) {
  __shared__ __align__(16) u16 STb[16][264];   // S^T bf16 copy: [jl][i], padded
  __shared__ __align__(16) u16 vnT[16][72];    // v_new^T [jl][c]
  // XCD swizzle: all 16 column-block WGs of one bh land on the same XCD (round-robin dispatch)
  const int bh = blockIdx.x & 7, jb = blockIdx.x >> 3;
  const int b = bh >> 2, h = bh & 3;
  const int j0 = jb << 4;
  const int t = threadIdx.x, w = t >> 6, l = t & 63;
  const int lane15 = l & 15, quad = l >> 4;
  const float gamma = 1.0f / (1.0f + __expf(-decay[h]));
  const float alpha = __expf(log_alpha[h]);
  const float gC = __powf(gamma, 64.0f);
  const int c = w * 16 + lane15;               // chunk-row this lane owns in phases A/B
  const float gc = __powf(gamma, (float)c);
  for (int i = t; i < 2112; i += 256) reinterpret_cast<u32*>(&STb[0][0])[i] = 0u;
  f32x4 Sacc[4];
#pragma unroll
  for (int nt = 0; nt < 4; ++nt) Sacc[nt] = (f32x4){0.f, 0.f, 0.f, 0.f};

  const size_t chb = (size_t)bh * 128;
  const u16* wkA_b = wkA + chb * 16384;
  const u16* vA_b = vA + chb * 16384;
  const u16* wkg_b = wkgT + chb * 16384;
  const u16* intr_b = intra + chb * 4096;
  const u16* rkF_b = rkF + chb * 16384;

  // Double-buffered per-step register staging (token-pasted names; all indices compile-time).
  bf16x8 AwkA[8], Ark[8], Awkg[8], Ain[2]; ushort4 AvA;
  bf16x8 BwkA[8], Brk[8], Bwkg[8], Bin[2]; ushort4 BvA;

  // All loads contiguous: base + const + l*16B (fragment-major layouts).
#define LOADB(P, n_) do {                                                                  \
    const u16* wkA_n = wkA_b + (size_t)(n_) * 16384;                                       \
    const u16* vA_n = vA_b + (size_t)(n_) * 16384;                                         \
    const u16* wkg_n = wkg_b + (size_t)(n_) * 16384;                                       \
    const u16* intr_n = intr_b + (size_t)(n_) * 4096;                                      \
    const u16* rk_n = rkF_b + (size_t)(n_) * 16384;                                        \
    _Pragma("unroll")                                                                      \
    for (int kt = 0; kt < 8; ++kt)                                                         \
      P##wkA[kt] = *reinterpret_cast<const bf16x8*>(&wkA_n[kt * 2048 + w * 512 + l * 8]);  \
    P##vA = *reinterpret_cast<const ushort4*>(&vA_n[jb * 1024 + w * 256 + l * 4]);         \
    _Pragma("unroll")                                                                      \
    for (int kt = 0; kt < 8; ++kt)                                                         \
      P##rk[kt] = *reinterpret_cast<const bf16x8*>(&rk_n[kt * 2048 + w * 512 + l * 8]);    \
    _Pragma("unroll")                                                                      \
    for (int kt = 0; kt < 2; ++kt)                                                         \
      P##in[kt] = *reinterpret_cast<const bf16x8*>(&intr_n[w * 1024 + kt * 512 + l * 8]);  \
    _Pragma("unroll")                                                                      \
    for (int nt = 0; nt < 4; ++nt)                                                         \
      _Pragma("unroll")                                                                    \
      for (int kt = 0; kt < 2; ++kt)                                                       \
        P##wkg[nt * 2 + kt] =                                                              \
            *reinterpret_cast<const bf16x8*>(&wkg_n[w * 4096 + nt * 1024 + kt * 512 + l * 8]); \
  } while (0)

  // Raw barrier via compiler-modeled builtins only (no memory clobber, no vmcnt drain).
#define KBAR() do {                                              \
    __builtin_amdgcn_s_waitcnt(0xC07F);                          \
    __builtin_amdgcn_s_barrier();                                \
    __builtin_amdgcn_sched_barrier(0);                           \
  } while (0)

#define STEP(P, Q, n_, do_pf) do {                                                         \
    if (do_pf) LOADB(Q, (n_) + 1); /* issue next step's loads before waiting */            \
    KBAR(); /* (a) STb from prev phase C visible */                                        \
    bf16x8 aS[8];                                                                          \
    _Pragma("unroll")                                                                      \
    for (int kt = 0; kt < 8; ++kt)                                                         \
      aS[kt] = *reinterpret_cast<const bf16x8*>(&STb[lane15][kt * 32 + quad * 8]);         \
    /* phase A: P^T = S^T @ wkA^T (2 parallel 4-chains); v_new^T = vA^T - P^T */           \
    f32x4 a0 = (f32x4){0.f, 0.f, 0.f, 0.f}, a1 = (f32x4){0.f, 0.f, 0.f, 0.f};              \
    _Pragma("unroll")                                                                      \
    for (int kt = 0; kt < 4; ++kt) a0 = mfma16(aS[kt], P##wkA[kt], a0);                    \
    _Pragma("unroll")                                                                      \
    for (int kt = 4; kt < 8; ++kt) a1 = mfma16(aS[kt], P##wkA[kt], a1);                    \
    vnT[quad * 4 + 0][c] = f2bf(bf2f(P##vA.x) - a0[0] - a1[0]);                            \
    vnT[quad * 4 + 1][c] = f2bf(bf2f(P##vA.y) - a0[1] - a1[1]);                            \
    vnT[quad * 4 + 2][c] = f2bf(bf2f(P##vA.z) - a0[2] - a1[2]);                            \
    vnT[quad * 4 + 3][c] = f2bf(bf2f(P##vA.w) - a0[3] - a1[3]);                            \
    /* S^T @ rk (needs only aS) + Sacc decay: hoisted above barrier (b), off vnT path */   \
    f32x4 r0 = (f32x4){0.f, 0.f, 0.f, 0.f}, r1 = (f32x4){0.f, 0.f, 0.f, 0.f};              \
    _Pragma("unroll")                                                                      \
    for (int kt = 0; kt < 4; ++kt) r0 = mfma16(aS[kt], P##rk[kt], r0);                     \
    _Pragma("unroll")                                                                      \
    for (int kt = 4; kt < 8; ++kt) r1 = mfma16(aS[kt], P##rk[kt], r1);                     \
    _Pragma("unroll")                                                                      \
    for (int nt = 0; nt < 4; ++nt)                                                         \
      _Pragma("unroll")                                                                    \
      for (int r = 0; r < 4; ++r) Sacc[nt][r] *= gC;                                       \
    KBAR(); /* (b) vnT visible */                                                          \
    bf16x8 aV[2];                                                                          \
    _Pragma("unroll")                                                                      \
    for (int kt = 0; kt < 2; ++kt)                                                         \
      aV[kt] = *reinterpret_cast<const bf16x8*>(&vnT[lane15][kt * 32 + quad * 8]);         \
    /* phase C first: S^T := gC*S^T + v_new^T @ wkg (critical path to next barrier) */     \
    _Pragma("unroll")                                                                      \
    for (int nt = 0; nt < 4; ++nt) {                                                       \
      _Pragma("unroll")                                                                    \
      for (int kt = 0; kt < 2; ++kt) Sacc[nt] = mfma16(aV[kt], P##wkg[nt * 2 + kt], Sacc[nt]); \
      _Pragma("unroll")                                                                    \
      for (int r = 0; r < 4; ++r)                                                          \
        STb[quad * 4 + r][w * 64 + nt * 16 + lane15] = f2bf(Sacc[nt][r]);                  \
    }                                                                                      \
    /* phase B tail: o^T = diag(g^c)*(S^T @ rk^T) + v_new^T @ intra^T, *alpha, store */    \
    {                                                                                      \
      f32x4 i0 = (f32x4){0.f, 0.f, 0.f, 0.f};                                              \
      _Pragma("unroll")                                                                    \
      for (int kt = 0; kt < 2; ++kt) i0 = mfma16(aV[kt], P##in[kt], i0);                   \
      ushort4 ov;                                                                          \
      ov.x = f2bf(((r0[0] + r1[0]) * gc + i0[0]) * alpha);                                 \
      ov.y = f2bf(((r0[1] + r1[1]) * gc + i0[1]) * alpha);                                 \
      ov.z = f2bf(((r0[2] + r1[2]) * gc + i0[2]) * alpha);                                 \
      ov.w = f2bf(((r0[3] + r1[3]) * gc + i0[3]) * alpha);                                 \
      *reinterpret_cast<ushort4*>(&o[((size_t)(b * T_SEQ + (n_) * 64 + c)) * DM + h * HD + j0 + quad * 4]) = ov; \
    }                                                                                      \
  } while (0)

  LOADB(A, 0);
#pragma unroll 1
  for (int n = 0; n < 128; n += 2) {
    STEP(A, B, n, true);            // n+1 <= 127 always valid
    STEP(B, A, n + 1, (n + 2 < 128));
  }
#undef STEP
#undef KBAR
#undef LOADB
}

extern "C" void kernel_launch(void* const* d_in, const int* in_sizes, int n_in,
                              void* d_out, int out_size, void* d_ws, size_t ws_size,
                              hipStream_t stream) {
  const float* x = (const float*)d_in[0];
  const float* Ww = (const float*)d_in[1];
  const float* Wr = (const float*)d_in[2];
  const float* decay = (const float*)d_in[3];
  const float* lalpha = (const float*)d_in[4];

  char* ws = (char*)d_ws;
  size_t off = 0;
  auto alloc = [&](size_t bytes) {
    char* p = ws + off;
    off += (bytes + 255) & ~(size_t)255;
    return p;
  };
  u16* xb16 = (u16*)alloc(33554432);   // (B,T,D) bf16 x   (later aliased as o)
  u16* rk16 = (u16*)alloc(33554432);   // (B,T,D) bf16 rk
  u16* v16  = (u16*)alloc(33554432);   // (B,T,D) bf16 v   (later aliased as rkF)
  u16* vAb  = (u16*)alloc(33554432);   // (BH,N) fragment-major vA
  u16* wkAb = (u16*)alloc(33554432);   // (BH,N) fragment-major wkA
  u16* wkgb = (u16*)alloc(33554432);   // (BH,N) fragment-major wkg
  u16* intrb = (u16*)alloc(8388608);   // (BH,N) fragment-major intra
  u16* Ww16 = (u16*)alloc(2097152);
  u16* Wr16 = (u16*)alloc(2097152);
  u16* o16 = xb16;   // alias: xb16 dead after GEMM1
  u16* rkFb = v16;   // alias: v16 dead after k2 (krkF runs stream-ordered after k2)

  kconv<<<1024, 256, 0, stream>>>(Ww, Ww16, 262144);
  kconv<<<1024, 256, 0, stream>>>(Wr, Wr16, 262144);
  k_rk<<<16384, 256, 0, stream>>>(x, xb16, rk16);
  gemm_bt<true><<<1024, 256, 0, stream>>>(xb16, Ww16, v16, nullptr, nullptr, 16384, 1024, 1024);
  k2<<<1024, 256, 0, stream>>>(rk16, v16, vAb, wkAb, wkgb, intrb, decay);
  krkF<<<1024, 256, 0, stream>>>(rk16, rkFb);
  k3<<<128, 256, 0, stream>>>(rkFb, vAb, wkAb, wkgb, intrb, decay, lalpha, o16);
  gemm_bt<false><<<1024, 256, 0, stream>>>(o16, Wr16, nullptr, (float*)d_out, x, 16384, 1024, 1024);
}